// Round 8
// baseline (1534.367 us; speedup 1.0000x reference)
//
#include <hip/hip_runtime.h>

#define B_ 256
#define N_ 2048
#define A_ 256
#define M_ 256
#define H_ 8
#define KD_ 32
#define VD_ 32
#define O_ 256

typedef float f32x4 __attribute__((ext_vector_type(4)));
typedef __bf16 bf16x8 __attribute__((ext_vector_type(8)));
typedef unsigned short u16x8 __attribute__((ext_vector_type(8)));

union FragU { u16x8 u; bf16x8 b; };

__device__ __forceinline__ unsigned short f2bf(float f) {
  union { __bf16 b; unsigned short u; } c;
  c.b = (__bf16)f;                    // RNE; compiler pairs into v_cvt_pk_bf16_f32
  return c.u;
}
__device__ __forceinline__ float bf2f(unsigned short h) {
  return __uint_as_float(((unsigned int)h) << 16);
}

// async global->LDS, 16B per lane; LDS dest is wave-uniform base + lane*16 (HW)
__device__ __forceinline__ void gll16(const void* gsrc, void* ldst) {
  __builtin_amdgcn_global_load_lds(
      (const __attribute__((address_space(1))) void*)gsrc,
      (__attribute__((address_space(3))) void*)ldst, 16, 0, 0);
}

// ---------------------------------------------------------------------------
// K1 "front": ONE dispatch fusing three independent jobs (overlapped HBM
// streams: q_data 512MB + m_data 512MB):
//   blk 0..255    : reduce_q  (q_avg -> q), 256 thr, 4 n-groups, f32x4
//   blk 256..511  : pack wg/wo to fragment-linear bf16
//   blk 512..4607 : kv = m_data @ [key_w|value_w] -> kv [B*N][64] bf16.
//                   kv blocks build their own packed-weight copy in LDS from
//                   raw fp32 key/value weights (64KB, L2-resident) -> no
//                   dependency on the pack blocks.
// frag index: (((ct*8+kc)*64)+lane)*8+j -> W[kc*32+(lane>>4)*8+j][ct*16+(lane&15)]
// ---------------------------------------------------------------------------
__global__ void front(const float* __restrict__ qd, const float* __restrict__ qm,
                      const float* __restrict__ qw, float* __restrict__ q_out,
                      const float* __restrict__ gating_w,
                      const float* __restrict__ output_w,
                      const float* __restrict__ key_w,
                      const float* __restrict__ value_w,
                      unsigned short* __restrict__ wg,
                      unsigned short* __restrict__ wo,
                      const float* __restrict__ md,
                      unsigned short* __restrict__ kv) {
  __shared__ __attribute__((aligned(16))) unsigned short smem_u16[16384]; // 32KB
  int blk = blockIdx.x;
  int t = threadIdx.x;

  if (blk < 256) {
    // ---- reduce_q: one block per b, 256 thr (4 n-groups), f32x4 rows ----
    int b = blk;
    int l = t & 63, g = t >> 6;
    const float* qdb = qd + (size_t)b * N_ * A_;
    const float* qmb = qm + (size_t)b * N_;
    f32x4 sum = {0.f, 0.f, 0.f, 0.f};
    float msum = 0.f;
    for (int n = g; n < N_; n += 4) {
      float m = qmb[n];                        // wave-uniform -> scalar
      msum += m;
      f32x4 v = *(const f32x4*)(qdb + (size_t)n * A_ + l * 4);
      sum += m * v;
    }
    float* sb = (float*)smem_u16;              // s[4][256] = 4KB
    float* ms = sb + 1024;                     // [4]
    float* qavg = sb + 1040;                   // [256]
    *(f32x4*)&sb[g * 256 + l * 4] = sum;
    if (l == 0) ms[g] = msum;
    __syncthreads();
    {
      float tot = sb[t] + sb[256 + t] + sb[512 + t] + sb[768 + t];
      float mt = ms[0] + ms[1] + ms[2] + ms[3];
      qavg[t] = tot / (mt + 1e-10f);
    }
    __syncthreads();
    {
      float acc = 0.f;
      for (int a2 = 0; a2 < 256; a2++) acc += qavg[a2] * qw[a2 * 256 + t];
      q_out[b * 256 + t] = acc * 0.17677669529663687f;   // 32^-0.5
    }
    return;
  }
  if (blk < 512) {
    // ---- pack wg/wo ----
    int idx = (blk - 256) * 256 + t;           // 0..65535
    int j = idx & 7;
    int lane = (idx >> 3) & 63;
    int rest = idx >> 9;
    int kc = rest & 7, ct = rest >> 3;
    int row = kc * 32 + ((lane >> 4) << 3) + j;
    int col = ct * 16 + (lane & 15);
    wg[idx] = f2bf(gating_w[row * 256 + col]); // [A=256][H*VD=256]
    wo[idx] = f2bf(output_w[row * 256 + col]); // [H*VD=256][O=256]
    return;
  }
  // ---- kv GEMM: 128 rows/block; wave w: rows w*32 + rt*16 ----
  // stage packed [key|value] fragments into LDS (coalesced global reads,
  // scattered LDS writes; layout identical to the old global wkv)
  {
#pragma unroll 8
    for (int k = 0; k < 64; k++) {
      int e = k * 256 + t;                     // [row 0..255][col 0..63]
      int row = e >> 6, col = e & 63;
      float v = (col < 32) ? key_w[row * 32 + col] : value_w[row * 32 + (col - 32)];
      int kc = row >> 5, rowin = row & 31;
      int hi = rowin >> 3, j = rowin & 7;
      int ct = col >> 4, l15c = col & 15;
      int fidx = (((ct * 8 + kc) * 64) + hi * 16 + l15c) * 8 + j;
      smem_u16[fidx] = f2bf(v);
    }
  }
  __syncthreads();
  int w = t >> 6, l = t & 63, q = l >> 4, l15 = l & 15;
  size_t r0 = (size_t)(blk - 512) * 128;
  f32x4 acc[2][4] = {};
  for (int kc = 0; kc < 8; kc++) {
    FragU bfr[4];
#pragma unroll
    for (int ct = 0; ct < 4; ct++)
      bfr[ct].u = *(const u16x8*)(smem_u16 + (((ct * 8 + kc) * 64 + l) << 3));
    FragU af[2];
#pragma unroll
    for (int rt = 0; rt < 2; rt++) {
      size_t row = r0 + (size_t)(w * 32 + rt * 16 + l15);
      const float4* s4 = (const float4*)(md + row * 256 + kc * 32 + q * 8);
      float4 u0 = s4[0], u1 = s4[1];
      af[rt].u = (u16x8){f2bf(u0.x), f2bf(u0.y), f2bf(u0.z), f2bf(u0.w),
                         f2bf(u1.x), f2bf(u1.y), f2bf(u1.z), f2bf(u1.w)};
    }
#pragma unroll
    for (int ct = 0; ct < 4; ct++) {
      acc[0][ct] = __builtin_amdgcn_mfma_f32_16x16x32_bf16(af[0].b, bfr[ct].b, acc[0][ct], 0, 0, 0);
      acc[1][ct] = __builtin_amdgcn_mfma_f32_16x16x32_bf16(af[1].b, bfr[ct].b, acc[1][ct], 0, 0, 0);
    }
  }
#pragma unroll
  for (int rt = 0; rt < 2; rt++)
#pragma unroll
    for (int ct = 0; ct < 4; ct++)
#pragma unroll
      for (int r = 0; r < 4; r++) {
        size_t row = r0 + (size_t)(w * 32 + rt * 16 + q * 4 + r);
        kv[row * 64 + ct * 16 + l15] = f2bf(acc[rt][ct][r]);
      }
}

// ---------------------------------------------------------------------------
// K3: logits -> softmax -> weighted_avg.  one block per b, 1024 thr (16 waves).
// logits [8][2048] fp32 in LDS (64 KB). phase 3: 4-way n-split + LDS reduce.
// (R2-exact form — best measured.)
// ---------------------------------------------------------------------------
__global__ void attn_softmax(const unsigned short* __restrict__ kv,
                             const float* __restrict__ qv,
                             const float* __restrict__ qm,
                             float* __restrict__ wa) {
  int b = blockIdx.x, t = threadIdx.x;
  __shared__ float lg[8][2048];
  __shared__ float red[4][256];
  __shared__ float inv_s[8];
  const float* qb = qv + b * 256;
  const float* qmb = qm + (size_t)b * N_;
  // phase 1: logits (each thread 2 rows)
  for (int n = t; n < N_; n += 1024) {
    const u16x8* kr = (const u16x8*)(kv + ((size_t)(b * N_ + n)) * 64);
    float kf[32];
#pragma unroll
    for (int c8 = 0; c8 < 4; c8++) {
      u16x8 kk = kr[c8];
#pragma unroll
      for (int j = 0; j < 8; j++) kf[c8 * 8 + j] = bf2f(kk[j]);
    }
    float bias_n = 1e9f * (qmb[n] - 1.0f);
#pragma unroll
    for (int h = 0; h < 8; h++) {
      float d = 0.f;
#pragma unroll
      for (int c = 0; c < 32; c++) d += qb[h * 32 + c] * kf[c];
      lg[h][n] = d + bias_n;
    }
  }
  __syncthreads();
  // phase 2: softmax over n per head (first 256 threads, 32 lanes/head)
  if (t < 256) {
    int h = t >> 5, i = t & 31;
    float m = -3.0e38f;
    for (int n = i; n < N_; n += 32) m = fmaxf(m, lg[h][n]);
#pragma unroll
    for (int off = 16; off; off >>= 1) m = fmaxf(m, __shfl_xor(m, off));
    float s = 0.f;
    for (int n = i; n < N_; n += 32) {
      float e = __expf(lg[h][n] - m);
      lg[h][n] = e;
      s += e;
    }
#pragma unroll
    for (int off = 16; off; off >>= 1) s += __shfl_xor(s, off);
    if (i == 0) inv_s[h] = 1.0f / s;
  }
  __syncthreads();
  // phase 3: weighted sum of V, 4-way split over n
  {
    int c = t & 31, h = (t >> 5) & 7, nq = t >> 8;   // nq in 0..3
    const unsigned short* vb = kv + ((size_t)b * N_ + nq * 512) * 64 + 32 + c;
    const float* lgh = &lg[h][nq * 512];
    float acc = 0.f;
#pragma unroll 8
    for (int n = 0; n < 512; n++) acc += lgh[n] * bf2f(vb[(size_t)n * 64]);
    red[nq][t & 255] = acc;
  }
  __syncthreads();
  if (t < 256) {
    float r = red[0][t] + red[1][t] + red[2][t] + red[3][t];
    wa[b * 256 + t] = r * inv_s[t >> 5];
  }
}

// ---------------------------------------------------------------------------
// K4: gate = sigmoid(q_data @ gating_w + gb); P = gate * wa; out = P @ output_w + ob
// (R2-exact form — best measured.)  8192 blocks x 256 thr; 64 rows/block.
// Fused per 32-col group g: gate MFMA -> per-WAVE P transpose (no barrier) ->
// out MFMA k-slice (acc in regs). TWO single 16KB stage buffers, rotated so
// every global_load_lds flies under a compute phase:
//   [stage_wo(g) in flight] gate_mfma(g) | barrier A (drains wo) |
//   issue stage_wg(g+1), out_mfma(g)     | barrier B (drains wg) |
//   issue stage_wo(g+1), loop.
// LDS: 16+16+5+3 = 40KB -> 4 blocks/CU (16 waves/CU).
// ---------------------------------------------------------------------------
__launch_bounds__(256, 4)
__global__ void gate_out(const float* __restrict__ qd,
                         const unsigned short* __restrict__ wg,
                         const unsigned short* __restrict__ wo,
                         const float* __restrict__ wa,
                         const float* __restrict__ gb,
                         const float* __restrict__ ob,
                         float* __restrict__ out) {
  int blk = blockIdx.x;
  int b = blk >> 5, tile = blk & 31;
  int t = threadIdx.x;
  int w = t >> 6, l = t & 63, q = l >> 4, l15 = l & 15;
  __shared__ __attribute__((aligned(16))) unsigned short wsg[8192];   // wg slice, 16KB
  __shared__ __attribute__((aligned(16))) unsigned short wso[8192];   // wo slice, 16KB
  __shared__ __attribute__((aligned(16))) unsigned short Pt[4][16][40]; // per-wave 16x32, stride 40
  __shared__ float wa_s[256], gb_s[256], ob_s[256];
  wa_s[t] = wa[b * 256 + t];
  gb_s[t] = gb[t];
  ob_s[t] = ob[t];
  size_t rowbase = (size_t)b * N_ + tile * 64;

  // stage group 0 into both buffers
  {
    const char* wgb = (const char*)wg;           // group 0 wg: contiguous 16KB
    const char* wob = (const char*)wo;           // group 0 wo: ct*8KB chunks of 1KB
#pragma unroll
    for (int i = 0; i < 4; i++) {
      int ch = i * 4 + w;                        // wave-uniform chunk id 0..15
      gll16(wgb + ch * 1024 + l * 16, (char*)wsg + ch * 1024);
      gll16(wob + ch * 8192 + l * 16, (char*)wso + ch * 1024);
    }
  }

  // A fragments straight from global q_data (8 consecutive fp32/lane)
  FragU af[8];
  {
    const float* src = qd + (rowbase + (size_t)(w * 16 + l15)) * 256 + q * 8;
#pragma unroll
    for (int kc = 0; kc < 8; kc++) {
      float4 u0 = *(const float4*)(src + kc * 32);
      float4 u1 = *(const float4*)(src + kc * 32 + 4);
      af[kc].u = (u16x8){f2bf(u0.x), f2bf(u0.y), f2bf(u0.z), f2bf(u0.w),
                         f2bf(u1.x), f2bf(u1.y), f2bf(u1.z), f2bf(u1.w)};
    }
  }
  f32x4 acc[16] = {};
  __syncthreads();   // group-0 stage drained; wa_s/gb_s/ob_s ready

  for (int g = 0; g < 8; g++) {
    // ---- gate GEMM for this group's 32 cols (reads wsg; stage_wo(g) landed) ----
    f32x4 gacc[2] = {};
#pragma unroll
    for (int kc = 0; kc < 8; kc++) {
      FragU b0, b1;
      b0.u = *(const u16x8*)(wsg + (kc * 64 + l) * 8);           // ct2 = 0
      b1.u = *(const u16x8*)(wsg + ((8 + kc) * 64 + l) * 8);     // ct2 = 1
      gacc[0] = __builtin_amdgcn_mfma_f32_16x16x32_bf16(af[kc].b, b0.b, gacc[0], 0, 0, 0);
      gacc[1] = __builtin_amdgcn_mfma_f32_16x16x32_bf16(af[kc].b, b1.b, gacc[1], 0, 0, 0);
    }
    // epilogue: sigmoid * wa -> per-wave P tile (C-layout rows q*4+r, col l15)
#pragma unroll
    for (int ctl = 0; ctl < 2; ctl++) {
      int colg = ctl * 16 + l15;
      int col = g * 32 + colg;
      float wav = wa_s[col], gbv = gb_s[col];
#pragma unroll
      for (int r = 0; r < 4; r++) {
        float x = gacc[ctl][r] + gbv;
        float gate = 1.0f / (1.0f + __expf(-x));
        Pt[w][q * 4 + r][colg] = f2bf(wav * gate);
      }
    }
    // A-fragment of P (same wave wrote these rows -> lgkm ordering only)
    FragU pf;
    pf.u = *(const u16x8*)&Pt[w][l15][q * 8];

    __syncthreads();   // A: all waves done reading wsg (drains any vmem too)
    if (g < 7) {       // stage wg(g+1) -> hidden under out GEMM
      const char* wgb = (const char*)wg + (size_t)(g + 1) * 16384;
#pragma unroll
      for (int i = 0; i < 4; i++) {
        int ch = i * 4 + w;
        gll16(wgb + ch * 1024 + l * 16, (char*)wsg + ch * 1024);
      }
    }
    // ---- out GEMM: accumulate k-slice g into persistent acc (reads wso) ----
#pragma unroll
    for (int ct = 0; ct < 16; ct++) {
      FragU bo;
      bo.u = *(const u16x8*)(wso + (ct * 64 + l) * 8);
      acc[ct] = __builtin_amdgcn_mfma_f32_16x16x32_bf16(pf.b, bo.b, acc[ct], 0, 0, 0);
    }
    __syncthreads();   // B: all waves done reading wso; drains stage_wg(g+1)
    if (g < 7) {       // stage wo(g+1) -> hidden under next gate GEMM
      const char* wob = (const char*)wo + (size_t)(g + 1) * 1024;
#pragma unroll
      for (int i = 0; i < 4; i++) {
        int ch = i * 4 + w;
        gll16(wob + ch * 8192 + l * 16, (char*)wso + ch * 1024);
      }
    }
    // barrier A of next iteration drains stage_wo before out GEMM reads it
  }
  // store: 64 rows x 256 cols fp32
#pragma unroll
  for (int ct = 0; ct < 16; ct++) {
    int col = ct * 16 + l15;
    float obv = ob_s[col];
    size_t orow = (rowbase + (size_t)(w * 16 + q * 4)) * 256 + col;
#pragma unroll
    for (int r = 0; r < 4; r++)
      out[orow + (size_t)r * 256] = acc[ct][r] + obv;
  }
}

// ---------------------------------------------------------------------------
extern "C" void kernel_launch(void* const* d_in, const int* in_sizes, int n_in,
                              void* d_out, int out_size, void* d_ws, size_t ws_size,
                              hipStream_t stream) {
  const float* q_data   = (const float*)d_in[0];
  const float* m_data   = (const float*)d_in[1];
  const float* q_mask   = (const float*)d_in[2];
  // d_in[3] = bias: overwritten by the module, unused
  const float* query_w  = (const float*)d_in[4];
  const float* key_w    = (const float*)d_in[5];
  const float* value_w  = (const float*)d_in[6];
  const float* gating_w = (const float*)d_in[7];
  const float* gating_b = (const float*)d_in[8];
  const float* output_w = (const float*)d_in[9];
  const float* output_b = (const float*)d_in[10];
  float* out = (float*)d_out;

  char* ws = (char*)d_ws;
  float* q_ws            = (float*)(ws);                        // 256 KB
  float* wa_ws           = (float*)(ws + (256 << 10));          // 256 KB
  unsigned short* wg_ws  = (unsigned short*)(ws + (512 << 10)); // 128 KB
  unsigned short* wo_ws  = (unsigned short*)(ws + (640 << 10)); // 128 KB
  unsigned short* kv_ws  = (unsigned short*)(ws + (800 << 10)); // 64 MB

  front<<<4608, 256, 0, stream>>>(q_data, q_mask, query_w, q_ws,
                                  gating_w, output_w, key_w, value_w,
                                  wg_ws, wo_ws, m_data, kv_ws);
  attn_softmax<<<B_, 1024, 0, stream>>>(kv_ws, q_ws, q_mask, wa_ws);
  gate_out<<<(B_ * N_) / 64, 256, 0, stream>>>(q_data, wg_ws, wo_ws, wa_ws,
                                               gating_b, output_b, out);
}

// Round 9
// 1437.624 us; speedup vs baseline: 1.0673x; 1.0673x over previous
//
#include <hip/hip_runtime.h>

#define B_ 256
#define N_ 2048
#define A_ 256
#define M_ 256
#define H_ 8
#define KD_ 32
#define VD_ 32
#define O_ 256

typedef float f32x4 __attribute__((ext_vector_type(4)));
typedef __bf16 bf16x8 __attribute__((ext_vector_type(8)));
typedef unsigned short u16x8 __attribute__((ext_vector_type(8)));

union FragU { u16x8 u; bf16x8 b; };

__device__ __forceinline__ unsigned short f2bf(float f) {
  union { __bf16 b; unsigned short u; } c;
  c.b = (__bf16)f;                    // RNE; compiler pairs into v_cvt_pk_bf16_f32
  return c.u;
}
__device__ __forceinline__ float bf2f(unsigned short h) {
  return __uint_as_float(((unsigned int)h) << 16);
}

// async global->LDS, 16B per lane; LDS dest is wave-uniform base + lane*16 (HW)
__device__ __forceinline__ void gll16(const void* gsrc, void* ldst) {
  __builtin_amdgcn_global_load_lds(
      (const __attribute__((address_space(1))) void*)gsrc,
      (__attribute__((address_space(3))) void*)ldst, 16, 0, 0);
}

// ---------------------------------------------------------------------------
// K0: pack weights to bf16 fragment-linear layout for mfma_f32_16x16x32_bf16.
// frag index: (((ct*8 + kc)*64) + lane)*8 + j  ->  W[kc*32 + (lane>>4)*8 + j][ct*16 + (lane&15)]
// ---------------------------------------------------------------------------
__global__ void pack_weights(const float* __restrict__ gating_w,
                             const float* __restrict__ output_w,
                             const float* __restrict__ key_w,
                             const float* __restrict__ value_w,
                             unsigned short* __restrict__ wg,
                             unsigned short* __restrict__ wo,
                             unsigned short* __restrict__ wkv) {
  int idx = blockIdx.x * 256 + threadIdx.x;    // 0..65535
  int j = idx & 7;
  int lane = (idx >> 3) & 63;
  int rest = idx >> 9;
  int kc = rest & 7, ct = rest >> 3;
  int row = kc * 32 + ((lane >> 4) << 3) + j;
  int col = ct * 16 + (lane & 15);
  wg[idx] = f2bf(gating_w[row * 256 + col]);   // [A=256][H*VD=256]
  wo[idx] = f2bf(output_w[row * 256 + col]);   // [H*VD=256][O=256]
  if (idx < 16384) {                           // ct<4 here: ncols=64 (k|v)
    float v = (col < 32) ? key_w[row * 32 + col] : value_w[row * 32 + (col - 32)];
    wkv[idx] = f2bf(v);
  }
}

// ---------------------------------------------------------------------------
// K1: q_avg = masked mean over N, then q = (q_avg @ query_w) * KD^-0.5
// one block per b, 1024 threads. f32x4 loads: wave covers a full 1KB row.
// ---------------------------------------------------------------------------
__global__ void reduce_q(const float* __restrict__ qd, const float* __restrict__ qm,
                         const float* __restrict__ qw, float* __restrict__ q_out) {
  int b = blockIdx.x;
  int t = threadIdx.x;
  int l = t & 63, g = t >> 6;                  // 16 n-groups, wave-uniform g
  const float* qdb = qd + (size_t)b * N_ * A_;
  const float* qmb = qm + (size_t)b * N_;
  f32x4 sum = {0.f, 0.f, 0.f, 0.f};
  float msum = 0.f;
  for (int n = g; n < N_; n += 16) {
    float m = qmb[n];                          // wave-uniform -> scalar
    msum += m;
    f32x4 v = *(const f32x4*)(qdb + (size_t)n * A_ + l * 4);
    sum += m * v;
  }
  __shared__ float s[16][256];
  __shared__ float ms[16];
  __shared__ float qavg[256];
  *(f32x4*)&s[g][l * 4] = sum;
  if (l == 0) ms[g] = msum;
  __syncthreads();
  if (t < 256) {
    float tot = 0.f;
#pragma unroll
    for (int k = 0; k < 16; k++) tot += s[k][t];
    float mt = 0.f;
#pragma unroll
    for (int k = 0; k < 16; k++) mt += ms[k];
    qavg[t] = tot / (mt + 1e-10f);
  }
  __syncthreads();
  if (t < 256) {
    float acc = 0.f;
    for (int a2 = 0; a2 < 256; a2++) acc += qavg[a2] * qw[a2 * 256 + t];
    q_out[b * 256 + t] = acc * 0.17677669529663687f;   // 32^-0.5
  }
}

// ---------------------------------------------------------------------------
// K2: kv = m_data @ [key_w | value_w]  -> bf16 [B*N][64]
// 4096 blocks x 256 thr; 128 rows/block; wave w: rows w*32 + rt*16
// ---------------------------------------------------------------------------
__global__ void kv_gemm(const float* __restrict__ md,
                        const unsigned short* __restrict__ wkv,
                        unsigned short* __restrict__ kv) {
  int t = threadIdx.x;
  int w = t >> 6, l = t & 63, q = l >> 4, l15 = l & 15;
  size_t r0 = (size_t)blockIdx.x * 128;
  f32x4 acc[2][4] = {};
  for (int kc = 0; kc < 8; kc++) {
    FragU bfr[4];
#pragma unroll
    for (int ct = 0; ct < 4; ct++)
      bfr[ct].u = *(const u16x8*)(wkv + (((ct * 8 + kc) * 64 + l) << 3));
    FragU af[2];
#pragma unroll
    for (int rt = 0; rt < 2; rt++) {
      size_t row = r0 + (size_t)(w * 32 + rt * 16 + l15);
      const float4* s4 = (const float4*)(md + row * 256 + kc * 32 + q * 8);
      float4 u0 = s4[0], u1 = s4[1];
      af[rt].u = (u16x8){f2bf(u0.x), f2bf(u0.y), f2bf(u0.z), f2bf(u0.w),
                         f2bf(u1.x), f2bf(u1.y), f2bf(u1.z), f2bf(u1.w)};
    }
#pragma unroll
    for (int ct = 0; ct < 4; ct++) {
      acc[0][ct] = __builtin_amdgcn_mfma_f32_16x16x32_bf16(af[0].b, bfr[ct].b, acc[0][ct], 0, 0, 0);
      acc[1][ct] = __builtin_amdgcn_mfma_f32_16x16x32_bf16(af[1].b, bfr[ct].b, acc[1][ct], 0, 0, 0);
    }
  }
#pragma unroll
  for (int rt = 0; rt < 2; rt++)
#pragma unroll
    for (int ct = 0; ct < 4; ct++)
#pragma unroll
      for (int r = 0; r < 4; r++) {
        size_t row = r0 + (size_t)(w * 32 + rt * 16 + q * 4 + r);
        kv[row * 64 + ct * 16 + l15] = f2bf(acc[rt][ct][r]);
      }
}

// ---------------------------------------------------------------------------
// K3: logits -> softmax -> weighted_avg.  one block per b, 1024 thr (16 waves).
// logits [8][2048] fp32 in LDS (64 KB). phase 3: 4-way n-split + LDS reduce.
// ---------------------------------------------------------------------------
__global__ void attn_softmax(const unsigned short* __restrict__ kv,
                             const float* __restrict__ qv,
                             const float* __restrict__ qm,
                             float* __restrict__ wa) {
  int b = blockIdx.x, t = threadIdx.x;
  __shared__ float lg[8][2048];
  __shared__ float red[4][256];
  __shared__ float inv_s[8];
  const float* qb = qv + b * 256;
  const float* qmb = qm + (size_t)b * N_;
  // phase 1: logits (each thread 2 rows)
  for (int n = t; n < N_; n += 1024) {
    const u16x8* kr = (const u16x8*)(kv + ((size_t)(b * N_ + n)) * 64);
    float kf[32];
#pragma unroll
    for (int c8 = 0; c8 < 4; c8++) {
      u16x8 kk = kr[c8];
#pragma unroll
      for (int j = 0; j < 8; j++) kf[c8 * 8 + j] = bf2f(kk[j]);
    }
    float bias_n = 1e9f * (qmb[n] - 1.0f);
#pragma unroll
    for (int h = 0; h < 8; h++) {
      float d = 0.f;
#pragma unroll
      for (int c = 0; c < 32; c++) d += qb[h * 32 + c] * kf[c];
      lg[h][n] = d + bias_n;
    }
  }
  __syncthreads();
  // phase 2: softmax over n per head (first 256 threads, 32 lanes/head)
  if (t < 256) {
    int h = t >> 5, i = t & 31;
    float m = -3.0e38f;
    for (int n = i; n < N_; n += 32) m = fmaxf(m, lg[h][n]);
#pragma unroll
    for (int off = 16; off; off >>= 1) m = fmaxf(m, __shfl_xor(m, off));
    float s = 0.f;
    for (int n = i; n < N_; n += 32) {
      float e = __expf(lg[h][n] - m);
      lg[h][n] = e;
      s += e;
    }
#pragma unroll
    for (int off = 16; off; off >>= 1) s += __shfl_xor(s, off);
    if (i == 0) inv_s[h] = 1.0f / s;
  }
  __syncthreads();
  // phase 3: weighted sum of V, 4-way split over n
  {
    int c = t & 31, h = (t >> 5) & 7, nq = t >> 8;   // nq in 0..3
    const unsigned short* vb = kv + ((size_t)b * N_ + nq * 512) * 64 + 32 + c;
    const float* lgh = &lg[h][nq * 512];
    float acc = 0.f;
#pragma unroll 8
    for (int n = 0; n < 512; n++) acc += lgh[n] * bf2f(vb[(size_t)n * 64]);
    red[nq][t & 255] = acc;
  }
  __syncthreads();
  if (t < 256) {
    float r = red[0][t] + red[1][t] + red[2][t] + red[3][t];
    wa[b * 256 + t] = r * inv_s[t >> 5];
  }
}

// ---------------------------------------------------------------------------
// K4: gate = sigmoid(q_data @ gating_w + gb); P = gate * wa; out = P @ output_w + ob
// 8192 blocks x 256 thr; 64 rows/block.
// Fused per 32-col group g: gate MFMA -> per-WAVE P transpose (no barrier) ->
// out MFMA k-slice (acc in regs). TWO single 16KB stage buffers, rotated so
// every global_load_lds flies under a compute phase:
//   [stage_wo(g) in flight] gate_mfma(g) | barrier A (drains wo) |
//   issue stage_wg(g+1), out_mfma(g)     | barrier B (drains wg) |
//   issue stage_wo(g+1), loop.
// LDS: 16+16+5+3 = 40KB -> 4 blocks/CU (16 waves/CU).
// ---------------------------------------------------------------------------
__launch_bounds__(256, 4)
__global__ void gate_out(const float* __restrict__ qd,
                         const unsigned short* __restrict__ wg,
                         const unsigned short* __restrict__ wo,
                         const float* __restrict__ wa,
                         const float* __restrict__ gb,
                         const float* __restrict__ ob,
                         float* __restrict__ out) {
  int blk = blockIdx.x;
  int b = blk >> 5, tile = blk & 31;
  int t = threadIdx.x;
  int w = t >> 6, l = t & 63, q = l >> 4, l15 = l & 15;
  __shared__ __attribute__((aligned(16))) unsigned short wsg[8192];   // wg slice, 16KB
  __shared__ __attribute__((aligned(16))) unsigned short wso[8192];   // wo slice, 16KB
  __shared__ __attribute__((aligned(16))) unsigned short Pt[4][16][40]; // per-wave 16x32, stride 40
  __shared__ float wa_s[256], gb_s[256], ob_s[256];
  wa_s[t] = wa[b * 256 + t];
  gb_s[t] = gb[t];
  ob_s[t] = ob[t];
  size_t rowbase = (size_t)b * N_ + tile * 64;

  // stage group 0 into both buffers
  {
    const char* wgb = (const char*)wg;           // group 0 wg: contiguous 16KB
    const char* wob = (const char*)wo;           // group 0 wo: ct*8KB chunks of 1KB
#pragma unroll
    for (int i = 0; i < 4; i++) {
      int ch = i * 4 + w;                        // wave-uniform chunk id 0..15
      gll16(wgb + ch * 1024 + l * 16, (char*)wsg + ch * 1024);
      gll16(wob + ch * 8192 + l * 16, (char*)wso + ch * 1024);
    }
  }

  // A fragments straight from global q_data (8 consecutive fp32/lane)
  FragU af[8];
  {
    const float* src = qd + (rowbase + (size_t)(w * 16 + l15)) * 256 + q * 8;
#pragma unroll
    for (int kc = 0; kc < 8; kc++) {
      float4 u0 = *(const float4*)(src + kc * 32);
      float4 u1 = *(const float4*)(src + kc * 32 + 4);
      af[kc].u = (u16x8){f2bf(u0.x), f2bf(u0.y), f2bf(u0.z), f2bf(u0.w),
                         f2bf(u1.x), f2bf(u1.y), f2bf(u1.z), f2bf(u1.w)};
    }
  }
  f32x4 acc[16] = {};
  __syncthreads();   // group-0 stage drained; wa_s/gb_s/ob_s ready

  for (int g = 0; g < 8; g++) {
    // ---- gate GEMM for this group's 32 cols (reads wsg; stage_wo(g) already landed) ----
    f32x4 gacc[2] = {};
#pragma unroll
    for (int kc = 0; kc < 8; kc++) {
      FragU b0, b1;
      b0.u = *(const u16x8*)(wsg + (kc * 64 + l) * 8);           // ct2 = 0
      b1.u = *(const u16x8*)(wsg + ((8 + kc) * 64 + l) * 8);     // ct2 = 1
      gacc[0] = __builtin_amdgcn_mfma_f32_16x16x32_bf16(af[kc].b, b0.b, gacc[0], 0, 0, 0);
      gacc[1] = __builtin_amdgcn_mfma_f32_16x16x32_bf16(af[kc].b, b1.b, gacc[1], 0, 0, 0);
    }
    // epilogue: sigmoid * wa -> per-wave P tile (C-layout rows q*4+r, col l15)
#pragma unroll
    for (int ctl = 0; ctl < 2; ctl++) {
      int colg = ctl * 16 + l15;
      int col = g * 32 + colg;
      float wav = wa_s[col], gbv = gb_s[col];
#pragma unroll
      for (int r = 0; r < 4; r++) {
        float x = gacc[ctl][r] + gbv;
        float gate = 1.0f / (1.0f + __expf(-x));
        Pt[w][q * 4 + r][colg] = f2bf(wav * gate);
      }
    }
    // A-fragment of P (same wave wrote these rows -> lgkm ordering only)
    FragU pf;
    pf.u = *(const u16x8*)&Pt[w][l15][q * 8];

    __syncthreads();   // A: all waves done reading wsg (drains any vmem too)
    if (g < 7) {       // stage wg(g+1) -> hidden under out GEMM
      const char* wgb = (const char*)wg + (size_t)(g + 1) * 16384;
#pragma unroll
      for (int i = 0; i < 4; i++) {
        int ch = i * 4 + w;
        gll16(wgb + ch * 1024 + l * 16, (char*)wsg + ch * 1024);
      }
    }
    // ---- out GEMM: accumulate k-slice g into persistent acc (reads wso) ----
#pragma unroll
    for (int ct = 0; ct < 16; ct++) {
      FragU bo;
      bo.u = *(const u16x8*)(wso + (ct * 64 + l) * 8);
      acc[ct] = __builtin_amdgcn_mfma_f32_16x16x32_bf16(pf.b, bo.b, acc[ct], 0, 0, 0);
    }
    __syncthreads();   // B: all waves done reading wso; drains stage_wg(g+1)
    if (g < 7) {       // stage wo(g+1) -> hidden under next gate GEMM
      const char* wob = (const char*)wo + (size_t)(g + 1) * 1024;
#pragma unroll
      for (int i = 0; i < 4; i++) {
        int ch = i * 4 + w;
        gll16(wob + ch * 8192 + l * 16, (char*)wso + ch * 1024);
      }
    }
    // barrier A of next iteration drains stage_wo before out GEMM reads it
  }
  // store: 64 rows x 256 cols fp32
#pragma unroll
  for (int ct = 0; ct < 16; ct++) {
    int col = ct * 16 + l15;
    float obv = ob_s[col];
    size_t orow = (rowbase + (size_t)(w * 16 + q * 4)) * 256 + col;
#pragma unroll
    for (int r = 0; r < 4; r++)
      out[orow + (size_t)r * 256] = acc[ct][r] + obv;
  }
}

// ---------------------------------------------------------------------------
extern "C" void kernel_launch(void* const* d_in, const int* in_sizes, int n_in,
                              void* d_out, int out_size, void* d_ws, size_t ws_size,
                              hipStream_t stream) {
  const float* q_data   = (const float*)d_in[0];
  const float* m_data   = (const float*)d_in[1];
  const float* q_mask   = (const float*)d_in[2];
  // d_in[3] = bias: overwritten by the module, unused
  const float* query_w  = (const float*)d_in[4];
  const float* key_w    = (const float*)d_in[5];
  const float* value_w  = (const float*)d_in[6];
  const float* gating_w = (const float*)d_in[7];
  const float* gating_b = (const float*)d_in[8];
  const float* output_w = (const float*)d_in[9];
  const float* output_b = (const float*)d_in[10];
  float* out = (float*)d_out;

  char* ws = (char*)d_ws;
  float* q_ws            = (float*)(ws);                        // 256 KB
  float* wa_ws           = (float*)(ws + (256 << 10));          // 256 KB
  unsigned short* wg_ws  = (unsigned short*)(ws + (512 << 10)); // 128 KB
  unsigned short* wo_ws  = (unsigned short*)(ws + (640 << 10)); // 128 KB
  unsigned short* wkv_ws = (unsigned short*)(ws + (768 << 10)); // 32 KB
  unsigned short* kv_ws  = (unsigned short*)(ws + (800 << 10)); // 64 MB

  pack_weights<<<256, 256, 0, stream>>>(gating_w, output_w, key_w, value_w,
                                        wg_ws, wo_ws, wkv_ws);
  reduce_q<<<B_, 1024, 0, stream>>>(q_data, q_mask, query_w, q_ws);
  kv_gemm<<<(B_ * N_) / 128, 256, 0, stream>>>(m_data, wkv_ws, kv_ws);
  attn_softmax<<<B_, 1024, 0, stream>>>(kv_ws, q_ws, q_mask, wa_ws);
  gate_out<<<(B_ * N_) / 64, 256, 0, stream>>>(q_data, wg_ws, wo_ws, wa_ws,
                                               gating_b, output_b, out);
}